// Round 5
// baseline (378.976 us; speedup 1.0000x reference)
//
#include <hip/hip_runtime.h>
#include <hip/hip_bf16.h>
#include <math.h>

#define HDIM 1024
#define IDIM 4096
#define NE 8
#define NTOK 2048
#define PADROWS 256

typedef __attribute__((ext_vector_type(8))) short bf16x8;
typedef __attribute__((ext_vector_type(4))) float f32x4;

__device__ __forceinline__ unsigned int f2bf(float f) {
    unsigned int u = __float_as_uint(f);
    u = (u + 0x7FFFu + ((u >> 16) & 1u)) >> 16;   // RNE
    return u;
}

__device__ __forceinline__ unsigned int pkbf2(float lo, float hi) {
    union { __hip_bfloat162 h; unsigned int u; } cv;
    cv.h = __float22bfloat162_rn(make_float2(lo, hi));   // v_cvt_pk_bf16_f32
    return cv.u;
}

// ---------------- Router: fp64 logits, argmax (first-max tie-break) -------------
__global__ __launch_bounds__(256) void router_k(const float* __restrict__ x,
                                                const float* __restrict__ rw,
                                                const float* __restrict__ rb,
                                                int* __restrict__ eidx,
                                                int* __restrict__ counts) {
    const int wave = threadIdx.x >> 6, lane = threadIdx.x & 63;
    const int t = blockIdx.x * 4 + wave;
    if (t >= NTOK) return;
    double acc[NE];
#pragma unroll
    for (int e = 0; e < NE; e++) acc[e] = 0.0;
    for (int h = lane; h < HDIM; h += 64) {
        double xv = (double)x[(size_t)t * HDIM + h];
        const float4* rwp = (const float4*)&rw[h * NE];
        float4 r0 = rwp[0], r1 = rwp[1];
        acc[0] += xv * (double)r0.x;  acc[1] += xv * (double)r0.y;
        acc[2] += xv * (double)r0.z;  acc[3] += xv * (double)r0.w;
        acc[4] += xv * (double)r1.x;  acc[5] += xv * (double)r1.y;
        acc[6] += xv * (double)r1.z;  acc[7] += xv * (double)r1.w;
    }
#pragma unroll
    for (int m = 32; m >= 1; m >>= 1) {
#pragma unroll
        for (int e = 0; e < NE; e++) acc[e] += __shfl_xor(acc[e], m);
    }
    if (lane == 0) {
        double best = acc[0] + (double)rb[0];
        int be = 0;
#pragma unroll
        for (int e = 1; e < NE; e++) {
            double v = acc[e] + (double)rb[e];
            if (v > best) { best = v; be = e; }
        }
        eidx[t] = be;
        atomicAdd(&counts[be], 1);
    }
}

__global__ void scan_k(const int* __restrict__ counts, int* __restrict__ offsets) {
    if (threadIdx.x == 0 && blockIdx.x == 0) {
        int s = 0;
        for (int e = 0; e < NE; e++) { offsets[e] = s; s += counts[e]; }
        offsets[NE] = s;
    }
}

// ---------------- Gather: Xg[row] = bf16(x[t] + 0.1*game_emb[e]) ----------------
__global__ __launch_bounds__(256) void gather_k(const float* __restrict__ x,
                                                const float* __restrict__ gemb,
                                                const int* __restrict__ eidx,
                                                const int* __restrict__ offsets,
                                                int* __restrict__ cursors,
                                                int* __restrict__ rowmap,
                                                unsigned short* __restrict__ Xg) {
    __shared__ int srow, se;
    const int t = blockIdx.x;
    if (threadIdx.x == 0) {
        int e = eidx[t];
        int pos = atomicAdd(&cursors[e], 1);
        int row = offsets[e] + pos;
        rowmap[row] = t;
        srow = row; se = e;
    }
    __syncthreads();
    const int row = srow, e = se;
    const int c = threadIdx.x * 4;
    float4 xv = *(const float4*)&x[(size_t)t * HDIM + c];
    float4 gv = *(const float4*)&gemb[(size_t)e * HDIM + c];
    ushort4 o;
    o.x = (unsigned short)f2bf(xv.x + 0.1f * gv.x);
    o.y = (unsigned short)f2bf(xv.y + 0.1f * gv.y);
    o.z = (unsigned short)f2bf(xv.z + 0.1f * gv.z);
    o.w = (unsigned short)f2bf(xv.w + 0.1f * gv.w);
    *(ushort4*)&Xg[(size_t)row * HDIM + c] = o;
}

// ---------------- FFN1: Hbuf = bf16(gelu(Xg @ w1[e] + b1[e])) -------------------
// No LDS, no barriers. Wave tile 64x32; block = 4 waves sharing rows (L1 A-dedup).
// B read as strided scalar f32 from global (SGPR-base walk), cvt to bf16 in-reg.
__global__ __launch_bounds__(256, 4) void ffn1_k(
        const unsigned short* __restrict__ A,    // Xg [rows][1024]
        const float* __restrict__ Bw,            // w1 [e][1024][4096]
        const float* __restrict__ bias,          // b1 [e][4096]
        const int* __restrict__ offsets,
        unsigned short* __restrict__ Hout) {
    const int e = blockIdx.z;
    const int rend = offsets[e + 1];
    const int r0 = offsets[e] + blockIdx.y * 64;
    if (r0 >= rend) return;
    const int wave = threadIdx.x >> 6, lane = threadIdx.x & 63;
    const int l15 = lane & 15, l4 = lane >> 4;
    const int wc = blockIdx.x * 128 + wave * 32;
    const float* Be = Bw + (size_t)e * HDIM * IDIM;
    const unsigned short* Ag = A + (size_t)r0 * HDIM;

    int boff[2];
#pragma unroll
    for (int n = 0; n < 2; ++n) boff[n] = (l4 * 8) * IDIM + wc + n * 16 + l15;
    int aoff[4];
#pragma unroll
    for (int m = 0; m < 4; ++m) aoff[m] = (m * 16 + l15) * HDIM + l4 * 8;

    f32x4 acc[4][2] = {};
    bf16x8 B0[2][2], B1[2][2];    // [n][kh], all statically indexed

    auto loadB = [&](bf16x8 (&D)[2][2], int k0) {
#pragma unroll
        for (int n = 0; n < 2; ++n)
#pragma unroll
            for (int kh = 0; kh < 2; ++kh) {
                float f[8];
#pragma unroll
                for (int j = 0; j < 8; ++j)
                    f[j] = Be[(size_t)(k0 + kh * 32 + j) * IDIM + boff[n]];
                unsigned int* u = (unsigned int*)&D[n][kh];
#pragma unroll
                for (int j = 0; j < 4; ++j) u[j] = pkbf2(f[2 * j], f[2 * j + 1]);
            }
    };
    auto compute = [&](bf16x8 (&D)[2][2], int k0) {
#pragma unroll
        for (int kh = 0; kh < 2; ++kh) {
            bf16x8 af[4];
#pragma unroll
            for (int m = 0; m < 4; ++m)
                af[m] = *(const bf16x8*)&Ag[(size_t)(k0 + kh * 32) + aoff[m]];
#pragma unroll
            for (int m = 0; m < 4; ++m)
#pragma unroll
                for (int n = 0; n < 2; ++n)
                    acc[m][n] = __builtin_amdgcn_mfma_f32_16x16x32_bf16(af[m], D[n][kh], acc[m][n], 0, 0, 0);
        }
    };

    constexpr int NT = HDIM / 64;   // 16 (even)
    loadB(B0, 0);
    for (int t = 0; t < NT; t += 2) {
        loadB(B1, (t + 1) * 64);
        compute(B0, t * 64);
        if (t + 2 < NT) loadB(B0, (t + 2) * 64);
        compute(B1, (t + 1) * 64);
    }

#pragma unroll
    for (int m = 0; m < 4; ++m)
#pragma unroll
        for (int r = 0; r < 4; ++r) {
            int row = r0 + m * 16 + l4 * 4 + r;
            if (row < rend) {
#pragma unroll
                for (int n = 0; n < 2; ++n) {
                    int col = wc + n * 16 + l15;
                    float v = acc[m][n][r] + bias[(size_t)e * IDIM + col];
                    float g = 0.5f * v * (1.0f + erff(v * 0.70710678118654752f));
                    Hout[(size_t)row * IDIM + col] = (unsigned short)f2bf(g);
                }
            }
        }
}

// ---------------- FFN2: out[tok] = Hbuf @ w2[e] + b2[e] -------------------------
// 8 waves: 2 col-groups x 4 K-quarters (split-K in-block). LDS used only for the
// final cross-wave reduce (chunk-swizzled, conflict-free).
__global__ __launch_bounds__(512, 4) void ffn2_k(
        const unsigned short* __restrict__ A,    // Hbuf [rows][4096]
        const float* __restrict__ Bw,            // w2 [e][4096][1024]
        const float* __restrict__ bias,          // b2 [e][1024]
        const int* __restrict__ offsets,
        const int* __restrict__ rowmap,
        float* __restrict__ out) {
    __shared__ float Lds[8][64][32];             // 64 KB
    const int e = blockIdx.z;
    const int rend = offsets[e + 1];
    const int r0 = offsets[e] + blockIdx.y * 64;
    if (r0 >= rend) return;
    const int tid = threadIdx.x;
    const int wave = tid >> 6, lane = tid & 63;
    const int cg = wave & 1, kq = wave >> 1;
    const int l15 = lane & 15, l4 = lane >> 4;
    const int c0 = blockIdx.x * 64;
    const int wc = c0 + cg * 32;
    const float* Be = Bw + (size_t)e * IDIM * HDIM;
    const unsigned short* Ag = A + (size_t)r0 * IDIM;
    const int kbeg = kq * 1024;

    int boff[2];
#pragma unroll
    for (int n = 0; n < 2; ++n) boff[n] = (l4 * 8) * HDIM + wc + n * 16 + l15;
    int aoff[4];
#pragma unroll
    for (int m = 0; m < 4; ++m) aoff[m] = (m * 16 + l15) * IDIM + l4 * 8;

    f32x4 acc[4][2] = {};
    bf16x8 B0[2][2], B1[2][2];

    auto loadB = [&](bf16x8 (&D)[2][2], int k0) {
#pragma unroll
        for (int n = 0; n < 2; ++n)
#pragma unroll
            for (int kh = 0; kh < 2; ++kh) {
                float f[8];
#pragma unroll
                for (int j = 0; j < 8; ++j)
                    f[j] = Be[(size_t)(k0 + kh * 32 + j) * HDIM + boff[n]];
                unsigned int* u = (unsigned int*)&D[n][kh];
#pragma unroll
                for (int j = 0; j < 4; ++j) u[j] = pkbf2(f[2 * j], f[2 * j + 1]);
            }
    };
    auto compute = [&](bf16x8 (&D)[2][2], int k0) {
#pragma unroll
        for (int kh = 0; kh < 2; ++kh) {
            bf16x8 af[4];
#pragma unroll
            for (int m = 0; m < 4; ++m)
                af[m] = *(const bf16x8*)&Ag[(size_t)(k0 + kh * 32) + aoff[m]];
#pragma unroll
            for (int m = 0; m < 4; ++m)
#pragma unroll
                for (int n = 0; n < 2; ++n)
                    acc[m][n] = __builtin_amdgcn_mfma_f32_16x16x32_bf16(af[m], D[n][kh], acc[m][n], 0, 0, 0);
        }
    };

    constexpr int NT = 1024 / 64;   // 16 (even)
    loadB(B0, kbeg);
    for (int t = 0; t < NT; t += 2) {
        loadB(B1, kbeg + (t + 1) * 64);
        compute(B0, kbeg + t * 64);
        if (t + 2 < NT) loadB(B0, kbeg + (t + 2) * 64);
        compute(B1, kbeg + (t + 1) * 64);
    }

    // partials -> LDS, chunk-swizzled by (row & 7) for conflict-free b128 reads
#pragma unroll
    for (int m = 0; m < 4; ++m)
#pragma unroll
        for (int n = 0; n < 2; ++n)
#pragma unroll
            for (int r = 0; r < 4; ++r) {
                int wrow = m * 16 + l4 * 4 + r;
                int ncol = n * 16 + l15;
                int sch = ((ncol >> 2) ^ (wrow & 7)) * 4 + (ncol & 3);
                Lds[wave][wrow][sch] = acc[m][n][r];
            }
    __syncthreads();

    const int row = tid >> 3;
    const int c8 = (tid & 7) * 8;
    const int ccg = c8 >> 5, c32 = c8 & 31;
    f32x4 s0 = {}, s1 = {};
#pragma unroll
    for (int q = 0; q < 4; ++q) {
        int w = q * 2 + ccg;
        int ch0 = ((c32 >> 2) ^ (row & 7)) * 4;
        int ch1 = (((c32 >> 2) + 1) ^ (row & 7)) * 4;
        s0 += *(const f32x4*)&Lds[w][row][ch0];
        s1 += *(const f32x4*)&Lds[w][row][ch1];
    }
    const int grow = r0 + row;
    if (grow < rend) {
        const int tok = rowmap[grow];
        const float* bp = &bias[(size_t)e * HDIM + c0 + c8];
        s0 += *(const f32x4*)bp;
        s1 += *(const f32x4*)(bp + 4);
        float* op = &out[(size_t)tok * HDIM + c0 + c8];
        *(f32x4*)op = s0;
        *(f32x4*)(op + 4) = s1;
    }
}

// ---------------- launch ---------------------------------------------------------
extern "C" void kernel_launch(void* const* d_in, const int* in_sizes, int n_in,
                              void* d_out, int out_size, void* d_ws, size_t ws_size,
                              hipStream_t stream) {
    const float* x    = (const float*)d_in[0];
    const float* rw   = (const float*)d_in[1];
    const float* rb   = (const float*)d_in[2];
    const float* w1   = (const float*)d_in[3];
    const float* b1   = (const float*)d_in[4];
    const float* w2   = (const float*)d_in[5];
    const float* b2   = (const float*)d_in[6];
    const float* gemb = (const float*)d_in[7];
    float* out = (float*)d_out;

    // workspace: meta | Xg | Hbuf  (~23.6 MB)
    char* ws = (char*)d_ws;
    int* meta    = (int*)ws;
    int* counts  = meta;            // 8
    int* cursors = meta + 8;        // 8
    int* offsets = meta + 16;       // 9
    int* eidx    = meta + 32;       // 2048
    int* rowmap  = meta + 32 + NTOK;
    size_t off = 32768;
    unsigned short* Xg = (unsigned short*)(ws + off);
    off += (size_t)(NTOK + PADROWS) * HDIM * 2;
    unsigned short* Hbuf = (unsigned short*)(ws + off);

    hipMemsetAsync(counts, 0, 16 * sizeof(int), stream);
    router_k<<<NTOK / 4, 256, 0, stream>>>(x, rw, rb, eidx, counts);
    scan_k<<<1, 64, 0, stream>>>(counts, offsets);
    gather_k<<<NTOK, 256, 0, stream>>>(x, gemb, eidx, offsets, cursors, rowmap, Xg);
    // FFN1: streaming, no LDS. grid: 32 col-blocks x 32 row-blocks x 8 experts
    ffn1_k<<<dim3(IDIM / 128, NTOK / 64, NE), 256, 0, stream>>>(
        Xg, w1, b1, offsets, Hbuf);
    // FFN2: split-K=4 in-block, LDS reduce epilogue. 16 x 32 x 8
    ffn2_k<<<dim3(HDIM / 64, NTOK / 64, NE), 512, 0, stream>>>(
        Hbuf, w2, b2, offsets, rowmap, out);
}

// Round 6
// 212.568 us; speedup vs baseline: 1.7828x; 1.7828x over previous
//
#include <hip/hip_runtime.h>
#include <hip/hip_bf16.h>
#include <math.h>

#define HDIM 1024
#define IDIM 4096
#define NE 8
#define NTOK 2048
#define PADROWS 256

typedef __attribute__((ext_vector_type(8))) short bf16x8;
typedef __attribute__((ext_vector_type(4))) float f32x4;

__device__ __forceinline__ unsigned int f2bf(float f) {
    unsigned int u = __float_as_uint(f);
    u = (u + 0x7FFFu + ((u >> 16) & 1u)) >> 16;   // RNE
    return u;
}

__device__ __forceinline__ unsigned int pkbf2(float lo, float hi) {
    union { __hip_bfloat162 h; unsigned int u; } cv;
    cv.h = __float22bfloat162_rn(make_float2(lo, hi));   // v_cvt_pk_bf16_f32
    return cv.u;
}

template<typename T, typename U>
__device__ __forceinline__ void gld16(const T* g, U* l) {
    __builtin_amdgcn_global_load_lds((const __attribute__((address_space(1))) void*)g,
                                     (__attribute__((address_space(3))) void*)l, 16, 0, 0);
}

// ---------------- Router: fp64 logits, argmax (first-max tie-break) -------------
__global__ __launch_bounds__(256) void router_k(const float* __restrict__ x,
                                                const float* __restrict__ rw,
                                                const float* __restrict__ rb,
                                                int* __restrict__ eidx,
                                                int* __restrict__ counts) {
    const int wave = threadIdx.x >> 6, lane = threadIdx.x & 63;
    const int t = blockIdx.x * 4 + wave;
    if (t >= NTOK) return;
    double acc[NE];
#pragma unroll
    for (int e = 0; e < NE; e++) acc[e] = 0.0;
    for (int h = lane; h < HDIM; h += 64) {
        double xv = (double)x[(size_t)t * HDIM + h];
        const float4* rwp = (const float4*)&rw[h * NE];
        float4 r0 = rwp[0], r1 = rwp[1];
        acc[0] += xv * (double)r0.x;  acc[1] += xv * (double)r0.y;
        acc[2] += xv * (double)r0.z;  acc[3] += xv * (double)r0.w;
        acc[4] += xv * (double)r1.x;  acc[5] += xv * (double)r1.y;
        acc[6] += xv * (double)r1.z;  acc[7] += xv * (double)r1.w;
    }
#pragma unroll
    for (int m = 32; m >= 1; m >>= 1) {
#pragma unroll
        for (int e = 0; e < NE; e++) acc[e] += __shfl_xor(acc[e], m);
    }
    if (lane == 0) {
        double best = acc[0] + (double)rb[0];
        int be = 0;
#pragma unroll
        for (int e = 1; e < NE; e++) {
            double v = acc[e] + (double)rb[e];
            if (v > best) { best = v; be = e; }
        }
        eidx[t] = be;
        atomicAdd(&counts[be], 1);
    }
}

__global__ void scan_k(const int* __restrict__ counts, int* __restrict__ offsets) {
    if (threadIdx.x == 0 && blockIdx.x == 0) {
        int s = 0;
        for (int e = 0; e < NE; e++) { offsets[e] = s; s += counts[e]; }
        offsets[NE] = s;
    }
}

// ---------------- Gather: Xg[row] = bf16(x[t] + 0.1*game_emb[e]) ----------------
__global__ __launch_bounds__(256) void gather_k(const float* __restrict__ x,
                                                const float* __restrict__ gemb,
                                                const int* __restrict__ eidx,
                                                const int* __restrict__ offsets,
                                                int* __restrict__ cursors,
                                                int* __restrict__ rowmap,
                                                unsigned short* __restrict__ Xg) {
    __shared__ int srow, se;
    const int t = blockIdx.x;
    if (threadIdx.x == 0) {
        int e = eidx[t];
        int pos = atomicAdd(&cursors[e], 1);
        int row = offsets[e] + pos;
        rowmap[row] = t;
        srow = row; se = e;
    }
    __syncthreads();
    const int row = srow, e = se;
    const int c = threadIdx.x * 4;
    float4 xv = *(const float4*)&x[(size_t)t * HDIM + c];
    float4 gv = *(const float4*)&gemb[(size_t)e * HDIM + c];
    ushort4 o;
    o.x = (unsigned short)f2bf(xv.x + 0.1f * gv.x);
    o.y = (unsigned short)f2bf(xv.y + 0.1f * gv.y);
    o.z = (unsigned short)f2bf(xv.z + 0.1f * gv.z);
    o.w = (unsigned short)f2bf(xv.w + 0.1f * gv.w);
    *(ushort4*)&Xg[(size_t)row * HDIM + c] = o;
}

// ---------------- Grouped GEMM: 128x64 tile, 32KB LDS, 4 blocks/CU --------------
// A bf16 [rows x lda] via global_load_lds (XOR k-slot swizzle, both-sides).
// B f32 [Kfull x ldbN] via global_load_lds raw (col-granule swizzle), transposed
// + converted to bf16 at fragment-read time (scalar ds_read_b32, 2-way free).
// Single-buffered, 2 __syncthreads per K-step (m97 structure); block-TLP pipelines.
// EPI 0: Hout = bf16(gelu(acc+b1)).
// EPI 1: split0 -> Yout[rowmap[row]] = acc+bias; split s>0 -> P[s-1][row] = acc.
template<int BM, int BN, int EPI>
__global__ __launch_bounds__(256, 4) void moe_gemm_k(
        const unsigned short* __restrict__ A, int lda, int Kfull, int ksplit,
        const float* __restrict__ Bw, int ldbN,
        const float* __restrict__ bias,
        const int* __restrict__ offsets, const int* __restrict__ rowmap,
        unsigned short* __restrict__ Hout, float* __restrict__ Yout,
        float* __restrict__ P, size_t pstride) {
    constexpr int MFRAG = BM / 32;     // 4: wave rows = 2
    constexpr int NFRAG = BN / 32;     // 2: wave cols = 2
    constexpr int NIA = BM / 32;       // A DMA instrs per wave (4)
    constexpr int NIB = BN / 16;       // B DMA instrs per wave (4)

    __shared__ __align__(16) unsigned short At[BM * 64];   // 16 KB
    __shared__ __align__(16) float Bt[64 * BN];            // 16 KB

    const int e = blockIdx.z & 7;
    const int split = blockIdx.z >> 3;
    const int rend = offsets[e + 1];
    const int r0 = offsets[e] + blockIdx.y * BM;
    if (r0 >= rend) return;
    const int c0 = blockIdx.x * BN;
    const int kbeg = split * ksplit;
    const int nt = ksplit / 64;
    const float* Be = Bw + (size_t)e * Kfull * ldbN;

    const int tid = threadIdx.x;
    const int wave = tid >> 6, lane = tid & 63;
    const int wr = (wave >> 1) * (MFRAG * 16);
    const int wc = (wave & 1) * (NFRAG * 16);
    const int l15 = lane & 15, l4 = lane >> 4;

    f32x4 acc[MFRAG][NFRAG] = {};

    for (int t = 0; t < nt; ++t) {
        const int kk = kbeg + t * 64;
        // ---- stage A: granule g=(row,pkb), content k-slot pkb^(row&7) ----
#pragma unroll
        for (int i = 0; i < NIA; ++i) {
            int gb = (wave * NIA + i) << 6;
            int g = gb + lane;
            int row = g >> 3, pkb = g & 7;
            const unsigned short* src =
                A + (size_t)(r0 + row) * lda + kk + ((pkb ^ (row & 7)) << 3);
            gld16(src, &At[(size_t)gb * 8]);
        }
        // ---- stage B raw f32: granule g=(k,cg), source col-granule cg^(((k>>3)&1)<<2) ----
#pragma unroll
        for (int i = 0; i < NIB; ++i) {
            int gb = (wave * NIB + i) << 6;
            int g = gb + lane;
            int k = g >> 4, cg = g & 15;
            int scg = cg ^ (((k >> 3) & 1) << 2);
            const float* src = Be + (size_t)(kk + k) * ldbN + c0 + (scg << 2);
            gld16(src, &Bt[(size_t)gb * 4]);
        }
        __syncthreads();   // compiler drains vmcnt before barrier
        // ---- compute ----
#pragma unroll
        for (int kh = 0; kh < 2; ++kh) {
            const int kb = kh * 4 + l4;
            bf16x8 af[MFRAG];
#pragma unroll
            for (int m = 0; m < MFRAG; ++m) {
                int row = wr + m * 16 + l15;
                af[m] = *(const bf16x8*)&At[(row * 8 + (kb ^ (row & 7))) * 8];
            }
#pragma unroll
            for (int n = 0; n < NFRAG; ++n) {
                int cswz = (wc + n * 16 + l15) ^ ((kb & 1) << 4);
                float f[8];
#pragma unroll
                for (int j = 0; j < 8; ++j)
                    f[j] = Bt[(kb * 8 + j) * BN + cswz];
                bf16x8 bfr;
                unsigned int* bu = (unsigned int*)&bfr;
#pragma unroll
                for (int j = 0; j < 4; ++j) bu[j] = pkbf2(f[2 * j], f[2 * j + 1]);
#pragma unroll
                for (int m = 0; m < MFRAG; ++m)
                    acc[m][n] = __builtin_amdgcn_mfma_f32_16x16x32_bf16(af[m], bfr, acc[m][n], 0, 0, 0);
            }
        }
        __syncthreads();
    }

    // ---- epilogue ----
#pragma unroll
    for (int m = 0; m < MFRAG; ++m) {
#pragma unroll
        for (int r = 0; r < 4; ++r) {
            const int row = r0 + wr + m * 16 + l4 * 4 + r;
            if (row < rend) {
                if constexpr (EPI == 0) {
#pragma unroll
                    for (int n = 0; n < NFRAG; ++n) {
                        int col = c0 + wc + n * 16 + l15;
                        float v = acc[m][n][r] + bias[(size_t)e * ldbN + col];
                        float g = 0.5f * v * (1.0f + erff(v * 0.70710678118654752f));
                        Hout[(size_t)row * IDIM + col] = (unsigned short)f2bf(g);
                    }
                } else if (split == 0) {
                    const int tt = rowmap[row];
#pragma unroll
                    for (int n = 0; n < NFRAG; ++n) {
                        int col = c0 + wc + n * 16 + l15;
                        Yout[(size_t)tt * HDIM + col] = acc[m][n][r] + bias[(size_t)e * ldbN + col];
                    }
                } else {
                    float* Ps = P + (size_t)(split - 1) * pstride;
#pragma unroll
                    for (int n = 0; n < NFRAG; ++n) {
                        int col = c0 + wc + n * 16 + l15;
                        Ps[(size_t)row * HDIM + col] = acc[m][n][r];
                    }
                }
            }
        }
    }
}

// ---------------- split-K combine: out[tok] += sum_s P[s][row] -------------------
__global__ __launch_bounds__(256) void reduce_k(const float* __restrict__ P,
                                                size_t pstride, int nparts,
                                                const int* __restrict__ rowmap,
                                                float* __restrict__ out) {
    const int row = blockIdx.x;
    const int t = rowmap[row];
    const int c = threadIdx.x * 4;
    f32x4 s = *(const f32x4*)&out[(size_t)t * HDIM + c];
    for (int p = 0; p < nparts; ++p)
        s += *(const f32x4*)&P[(size_t)p * pstride + (size_t)row * HDIM + c];
    *(f32x4*)&out[(size_t)t * HDIM + c] = s;
}

// ---------------- launch ---------------------------------------------------------
extern "C" void kernel_launch(void* const* d_in, const int* in_sizes, int n_in,
                              void* d_out, int out_size, void* d_ws, size_t ws_size,
                              hipStream_t stream) {
    const float* x    = (const float*)d_in[0];
    const float* rw   = (const float*)d_in[1];
    const float* rb   = (const float*)d_in[2];
    const float* w1   = (const float*)d_in[3];
    const float* b1   = (const float*)d_in[4];
    const float* w2   = (const float*)d_in[5];
    const float* b2   = (const float*)d_in[6];
    const float* gemb = (const float*)d_in[7];
    float* out = (float*)d_out;

    // workspace: meta | Xg | Hbuf | P[nsplit-1]
    char* ws = (char*)d_ws;
    int* meta    = (int*)ws;
    int* counts  = meta;            // 8
    int* cursors = meta + 8;        // 8
    int* offsets = meta + 16;       // 9
    int* eidx    = meta + 32;       // 2048
    int* rowmap  = meta + 32 + NTOK;
    size_t off = 32768;
    unsigned short* Xg = (unsigned short*)(ws + off);
    off += (size_t)(NTOK + PADROWS) * HDIM * 2;
    unsigned short* Hbuf = (unsigned short*)(ws + off);
    off += (size_t)(NTOK + PADROWS) * IDIM * 2;
    float* P = (float*)(ws + off);
    const size_t pstride = (size_t)NTOK * HDIM;   // elements per split partial
    int nsplit = 1;
    if (ws_size >= off + 3 * pstride * 4) nsplit = 4;
    else if (ws_size >= off + 1 * pstride * 4) nsplit = 2;

    hipMemsetAsync(counts, 0, 16 * sizeof(int), stream);
    router_k<<<NTOK / 4, 256, 0, stream>>>(x, rw, rb, eidx, counts);
    scan_k<<<1, 64, 0, stream>>>(counts, offsets);
    gather_k<<<NTOK, 256, 0, stream>>>(x, gemb, eidx, offsets, cursors, rowmap, Xg);
    // FFN1: [rows x 1024] @ w1[e] -> gelu -> Hbuf. ~1024 active blocks, 4/CU.
    moe_gemm_k<128, 64, 0><<<dim3(IDIM / 64, 6, NE), 256, 0, stream>>>(
        Xg, HDIM, HDIM, HDIM, w1, IDIM, b1, offsets, rowmap, Hbuf, nullptr, nullptr, 0);
    // FFN2: [rows x 4096] @ w2[e] + b2 -> out (split-K in z, direct stores + P)
    moe_gemm_k<128, 64, 1><<<dim3(HDIM / 64, 6, NE * nsplit), 256, 0, stream>>>(
        Hbuf, IDIM, IDIM, IDIM / nsplit, w2, HDIM, b2, offsets, rowmap, nullptr, out, P, pstride);
    if (nsplit > 1)
        reduce_k<<<NTOK, 256, 0, stream>>>(P, pstride, nsplit - 1, rowmap, out);
}

// Round 7
// 193.321 us; speedup vs baseline: 1.9604x; 1.0996x over previous
//
#include <hip/hip_runtime.h>
#include <hip/hip_bf16.h>
#include <math.h>

#define HDIM 1024
#define IDIM 4096
#define NE 8
#define NTOK 2048
#define PADROWS 256

typedef __attribute__((ext_vector_type(8))) short bf16x8;
typedef __attribute__((ext_vector_type(4))) float f32x4;

__device__ __forceinline__ unsigned int f2bf(float f) {
    unsigned int u = __float_as_uint(f);
    u = (u + 0x7FFFu + ((u >> 16) & 1u)) >> 16;   // RNE
    return u;
}

__device__ __forceinline__ unsigned int pkbf2(float lo, float hi) {
    union { __hip_bfloat162 h; unsigned int u; } cv;
    cv.h = __float22bfloat162_rn(make_float2(lo, hi));   // v_cvt_pk_bf16_f32
    return cv.u;
}

__device__ __forceinline__ float comp4(const float4& v, int c) {
    return c == 0 ? v.x : c == 1 ? v.y : c == 2 ? v.z : v.w;  // c is unroll-constant
}

__device__ __forceinline__ int swz8(int i) { return (i ^ (i >> 3)) & 7; }

// A&S 7.1.26 erf (|eps| < 1.5e-7) -> exact-GELU cheap
__device__ __forceinline__ float gelu_erf(float v) {
    float x = v * 0.70710678118654752f;
    float ax = fabsf(x);
    float t = 1.0f / (1.0f + 0.3275911f * ax);
    float p = t * (0.254829592f + t * (-0.284496736f + t * (1.421413741f +
              t * (-1.453152027f + t * 1.061405429f))));
    float er = 1.0f - p * __expf(-x * x);
    er = copysignf(er, v);
    return 0.5f * v * (1.0f + er);
}

template<typename T, typename U>
__device__ __forceinline__ void gld16(const T* g, U* l) {
    __builtin_amdgcn_global_load_lds((const __attribute__((address_space(1))) void*)g,
                                     (__attribute__((address_space(3))) void*)l, 16, 0, 0);
}

// ---------------- Router: fp64 logits, argmax (first-max tie-break) -------------
__global__ __launch_bounds__(256) void router_k(const float* __restrict__ x,
                                                const float* __restrict__ rw,
                                                const float* __restrict__ rb,
                                                int* __restrict__ eidx,
                                                int* __restrict__ counts) {
    const int wave = threadIdx.x >> 6, lane = threadIdx.x & 63;
    const int t = blockIdx.x * 4 + wave;
    if (t >= NTOK) return;
    double acc[NE];
#pragma unroll
    for (int e = 0; e < NE; e++) acc[e] = 0.0;
    for (int h = lane; h < HDIM; h += 64) {
        double xv = (double)x[(size_t)t * HDIM + h];
        const float4* rwp = (const float4*)&rw[h * NE];
        float4 r0 = rwp[0], r1 = rwp[1];
        acc[0] += xv * (double)r0.x;  acc[1] += xv * (double)r0.y;
        acc[2] += xv * (double)r0.z;  acc[3] += xv * (double)r0.w;
        acc[4] += xv * (double)r1.x;  acc[5] += xv * (double)r1.y;
        acc[6] += xv * (double)r1.z;  acc[7] += xv * (double)r1.w;
    }
#pragma unroll
    for (int m = 32; m >= 1; m >>= 1) {
#pragma unroll
        for (int e = 0; e < NE; e++) acc[e] += __shfl_xor(acc[e], m);
    }
    if (lane == 0) {
        double best = acc[0] + (double)rb[0];
        int be = 0;
#pragma unroll
        for (int e = 1; e < NE; e++) {
            double v = acc[e] + (double)rb[e];
            if (v > best) { best = v; be = e; }
        }
        eidx[t] = be;
        atomicAdd(&counts[be], 1);
    }
}

__global__ void scan_k(const int* __restrict__ counts, int* __restrict__ offsets) {
    if (threadIdx.x == 0 && blockIdx.x == 0) {
        int s = 0;
        for (int e = 0; e < NE; e++) { offsets[e] = s; s += counts[e]; }
        offsets[NE] = s;
    }
}

// ---------------- Gather: Xg[row] = bf16(x[t] + 0.1*game_emb[e]) ----------------
__global__ __launch_bounds__(256) void gather_k(const float* __restrict__ x,
                                                const float* __restrict__ gemb,
                                                const int* __restrict__ eidx,
                                                const int* __restrict__ offsets,
                                                int* __restrict__ cursors,
                                                int* __restrict__ rowmap,
                                                unsigned short* __restrict__ Xg) {
    __shared__ int srow, se;
    const int t = blockIdx.x;
    if (threadIdx.x == 0) {
        int e = eidx[t];
        int pos = atomicAdd(&cursors[e], 1);
        int row = offsets[e] + pos;
        rowmap[row] = t;
        srow = row; se = e;
    }
    __syncthreads();
    const int row = srow, e = se;
    const int c = threadIdx.x * 4;
    float4 xv = *(const float4*)&x[(size_t)t * HDIM + c];
    float4 gv = *(const float4*)&gemb[(size_t)e * HDIM + c];
    ushort4 o;
    o.x = (unsigned short)f2bf(xv.x + 0.1f * gv.x);
    o.y = (unsigned short)f2bf(xv.y + 0.1f * gv.y);
    o.z = (unsigned short)f2bf(xv.z + 0.1f * gv.z);
    o.w = (unsigned short)f2bf(xv.w + 0.1f * gv.w);
    *(ushort4*)&Xg[(size_t)row * HDIM + c] = o;
}

// ---------------- Grouped GEMM: 128x128 tile, all-b128 LDS, T14 prefetch --------
// A bf16 [rows x lda]: global_load_lds into At[2] (double-buffered), source slot
//   pre-swizzled: granule (row, s) holds k-octet s ^ swz8(row).
// B f32 [Kfull x ldbN]: reg-staged (8x float4 coalesced), cvt_pk -> 4x ds_write_b128
//   transposed into Bt[col][slot], slot = oct ^ swz8(col). All accesses give 8
//   distinct slots per 8 consecutive lanes -> conflict-free b128.
// Loop: writeB -> vmcnt(0)+lgkmcnt(0) (cheap: DMA issued a compute-phase ago) ->
//   barrier -> issue loadB/dmaA(t+1) -> MFMA compute -> barrier.
// EPI 0: Hout = bf16(gelu(acc+b1)).
// EPI 1: split0 -> Yout[rowmap[row]] = acc+bias; split s>0 -> P[s-1][row] = acc.
template<int EPI>
__global__ __launch_bounds__(256, 3) void moe_gemm_k(
        const unsigned short* __restrict__ A, int lda, int Kfull, int ksplit,
        const float* __restrict__ Bw, int ldbN,
        const float* __restrict__ bias,
        const int* __restrict__ offsets, const int* __restrict__ rowmap,
        unsigned short* __restrict__ Hout, float* __restrict__ Yout,
        float* __restrict__ P, size_t pstride) {
    __shared__ __align__(16) unsigned short At[2][128 * 64];   // 2 x 16 KB
    __shared__ __align__(16) unsigned short Bt[128 * 64];      // 16 KB

    const int e = blockIdx.z & 7;
    const int split = blockIdx.z >> 3;
    const int rend = offsets[e + 1];
    const int r0 = offsets[e] + blockIdx.y * 128;
    if (r0 >= rend) return;
    const int c0 = blockIdx.x * 128;
    const int kbeg = split * ksplit;
    const int nt = ksplit / 64;
    const float* Be = Bw + (size_t)e * Kfull * ldbN;

    const int tid = threadIdx.x;
    const int wave = tid >> 6, lane = tid & 63;
    const int wr = (wave >> 1) * 64, wc = (wave & 1) * 64;
    const int l15 = lane & 15, l4 = lane >> 4;

    // B staging coords: thread owns cols bcol..bcol+3, k-octet boct
    const int bcol = (tid & 31) * 4;
    const int boct = tid >> 5;
    const float* bsrc = Be + (size_t)boct * 8 * ldbN + c0 + bcol;
    int bwo[4];
#pragma unroll
    for (int i = 0; i < 4; ++i) {
        int col = bcol + i;
        bwo[i] = col * 64 + (boct ^ swz8(col)) * 8;
    }

    // A DMA coords: 4 granules/thread, wave-linear dest, swizzled source octet
    const unsigned short* adsrc[4];
    int adoff[4];
#pragma unroll
    for (int p = 0; p < 4; ++p) {
        int gidx = p * 256 + tid;
        int row = gidx >> 3, ps = gidx & 7;
        adsrc[p] = A + (size_t)(r0 + row) * lda + (ps ^ swz8(row)) * 8;
        adoff[p] = gidx * 8;
    }

    float4 fv[8];
    auto loadB = [&](int kabs) {
#pragma unroll
        for (int j = 0; j < 8; ++j)
            fv[j] = *(const float4*)&bsrc[(size_t)(kabs + j) * ldbN];
    };
    auto dmaA = [&](int kabs, int buf) {
#pragma unroll
        for (int p = 0; p < 4; ++p)
            gld16(adsrc[p] + kabs, &At[buf][adoff[p]]);
    };

    f32x4 acc[4][4];
#pragma unroll
    for (int m = 0; m < 4; ++m)
#pragma unroll
        for (int n = 0; n < 4; ++n) acc[m][n] = (f32x4){0.f, 0.f, 0.f, 0.f};

    loadB(kbeg);
    dmaA(kbeg, 0);
    for (int t = 0; t < nt; ++t) {
        const int cur = t & 1;
        // ---- write B tile from regs (auto-waits the fv loads) ----
#pragma unroll
        for (int i = 0; i < 4; ++i) {
            uint4 w;
            w.x = pkbf2(comp4(fv[0], i), comp4(fv[1], i));
            w.y = pkbf2(comp4(fv[2], i), comp4(fv[3], i));
            w.z = pkbf2(comp4(fv[4], i), comp4(fv[5], i));
            w.w = pkbf2(comp4(fv[6], i), comp4(fv[7], i));
            *(uint4*)&Bt[bwo[i]] = w;
        }
        // DMA(t) was issued a full compute-phase ago -> this drain is ~free
        asm volatile("s_waitcnt vmcnt(0) lgkmcnt(0)" ::: "memory");
        __builtin_amdgcn_s_barrier();
        __builtin_amdgcn_sched_barrier(0);
        if (t + 1 < nt) {          // prefetch lands during the MFMA phase below
            loadB(kbeg + (t + 1) * 64);
            dmaA(kbeg + (t + 1) * 64, cur ^ 1);
        }
        // ---- compute: all-b128 frag reads + 32 MFMA ----
#pragma unroll
        for (int kh = 0; kh < 2; ++kh) {
            const int kb = kh * 4 + l4;
            bf16x8 af[4], bfr[4];
#pragma unroll
            for (int m = 0; m < 4; ++m) {
                int row = wr + m * 16 + l15;
                af[m] = *(const bf16x8*)&At[cur][row * 64 + (kb ^ swz8(row)) * 8];
            }
#pragma unroll
            for (int n = 0; n < 4; ++n) {
                int col = wc + n * 16 + l15;
                bfr[n] = *(const bf16x8*)&Bt[col * 64 + (kb ^ swz8(col)) * 8];
            }
#pragma unroll
            for (int m = 0; m < 4; ++m)
#pragma unroll
                for (int n = 0; n < 4; ++n)
                    acc[m][n] = __builtin_amdgcn_mfma_f32_16x16x32_bf16(af[m], bfr[n], acc[m][n], 0, 0, 0);
        }
        __builtin_amdgcn_sched_barrier(0);
        __builtin_amdgcn_s_barrier();
    }

    // ---- epilogue ----
#pragma unroll
    for (int m = 0; m < 4; ++m) {
#pragma unroll
        for (int r = 0; r < 4; ++r) {
            const int row = r0 + wr + m * 16 + l4 * 4 + r;
            if (row < rend) {
                if constexpr (EPI == 0) {
#pragma unroll
                    for (int n = 0; n < 4; ++n) {
                        int col = c0 + wc + n * 16 + l15;
                        float v = acc[m][n][r] + bias[(size_t)e * ldbN + col];
                        Hout[(size_t)row * IDIM + col] = (unsigned short)f2bf(gelu_erf(v));
                    }
                } else if (split == 0) {
                    const int tt = rowmap[row];
#pragma unroll
                    for (int n = 0; n < 4; ++n) {
                        int col = c0 + wc + n * 16 + l15;
                        Yout[(size_t)tt * HDIM + col] = acc[m][n][r] + bias[(size_t)e * ldbN + col];
                    }
                } else {
                    float* Ps = P + (size_t)(split - 1) * pstride;
#pragma unroll
                    for (int n = 0; n < 4; ++n) {
                        int col = c0 + wc + n * 16 + l15;
                        Ps[(size_t)row * HDIM + col] = acc[m][n][r];
                    }
                }
            }
        }
    }
}

// ---------------- split-K combine: out[tok] += sum_s P[s][row] -------------------
__global__ __launch_bounds__(256) void reduce_k(const float* __restrict__ P,
                                                size_t pstride, int nparts,
                                                const int* __restrict__ rowmap,
                                                float* __restrict__ out) {
    const int row = blockIdx.x;
    const int t = rowmap[row];
    const int c = threadIdx.x * 4;
    f32x4 s = *(const f32x4*)&out[(size_t)t * HDIM + c];
    for (int p = 0; p < nparts; ++p)
        s += *(const f32x4*)&P[(size_t)p * pstride + (size_t)row * HDIM + c];
    *(f32x4*)&out[(size_t)t * HDIM + c] = s;
}

// ---------------- launch ---------------------------------------------------------
extern "C" void kernel_launch(void* const* d_in, const int* in_sizes, int n_in,
                              void* d_out, int out_size, void* d_ws, size_t ws_size,
                              hipStream_t stream) {
    const float* x    = (const float*)d_in[0];
    const float* rw   = (const float*)d_in[1];
    const float* rb   = (const float*)d_in[2];
    const float* w1   = (const float*)d_in[3];
    const float* b1   = (const float*)d_in[4];
    const float* w2   = (const float*)d_in[5];
    const float* b2   = (const float*)d_in[6];
    const float* gemb = (const float*)d_in[7];
    float* out = (float*)d_out;

    // workspace: meta | Xg | Hbuf | P[nsplit-1]
    char* ws = (char*)d_ws;
    int* meta    = (int*)ws;
    int* counts  = meta;            // 8
    int* cursors = meta + 8;        // 8
    int* offsets = meta + 16;       // 9
    int* eidx    = meta + 32;       // 2048
    int* rowmap  = meta + 32 + NTOK;
    size_t off = 32768;
    unsigned short* Xg = (unsigned short*)(ws + off);
    off += (size_t)(NTOK + PADROWS) * HDIM * 2;
    unsigned short* Hbuf = (unsigned short*)(ws + off);
    off += (size_t)(NTOK + PADROWS) * IDIM * 2;
    float* P = (float*)(ws + off);
    const size_t pstride = (size_t)NTOK * HDIM;
    int nsplit = 1;
    if (ws_size >= off + 3 * pstride * 4) nsplit = 4;
    else if (ws_size >= off + 1 * pstride * 4) nsplit = 2;

    hipMemsetAsync(counts, 0, 16 * sizeof(int), stream);
    router_k<<<NTOK / 4, 256, 0, stream>>>(x, rw, rb, eidx, counts);
    scan_k<<<1, 64, 0, stream>>>(counts, offsets);
    gather_k<<<NTOK, 256, 0, stream>>>(x, gemb, eidx, offsets, cursors, rowmap, Xg);
    // FFN1: [rows x 1024] @ w1[e] -> gelu -> Hbuf. grid 32x3x8 = 768 blocks.
    moe_gemm_k<0><<<dim3(IDIM / 128, 3, NE), 256, 0, stream>>>(
        Xg, HDIM, HDIM, HDIM, w1, IDIM, b1, offsets, rowmap, Hbuf, nullptr, nullptr, 0);
    // FFN2: [rows x 4096] @ w2[e] + b2 -> out (split-K in z; split0 direct-stores
    // the full output incl. bias, so no out-memset needed).
    moe_gemm_k<1><<<dim3(HDIM / 128, 3, NE * nsplit), 256, 0, stream>>>(
        Hbuf, IDIM, IDIM, IDIM / nsplit, w2, HDIM, b2, offsets, rowmap, nullptr, out, P, pstride);
    if (nsplit > 1)
        reduce_k<<<NTOK, 256, 0, stream>>>(P, pstride, nsplit - 1, rowmap, out);
}